// Round 4
// baseline (116878.845 us; speedup 1.0000x reference)
//
#include <hip/hip_runtime.h>
#include <stdint.h>

// LSTM: 2-layer LSTMCell H=2048, T=2048, future=128.
// R4: ONE persistent cooperative kernel, layer-1 on blocks 0..127 and
// layer-2 on blocks 128..255, pipelined with 1-step skew via a 16-slot
// epoch-tagged exchange ring. All recurrent weights VGPR-resident
// (L1: 128 f/thread, L2: 256 f/thread). Phases B (IG2 GEMM) and D
// (streamed future kernel) are eliminated.
//
// Workspace layout:
//   h1ex [16][2048] u64 @ 0        (h1 ring: value|epoch packed)
//   h2ex [16][2048] u64 @ 256K
//   H2   [2048][2048] f32 @ 512K   (h2 history for the out-projection)

typedef unsigned long long u64;
typedef unsigned int u32;

#define HD 2048
#define TT 2048
#define FUT 128
#define NS 16

#define LD4(p) (*reinterpret_cast<const float4*>(p))
#define KEEPF(x) asm volatile("" : "+v"(x))
#define KEEP4(W) do { KEEPF(W.x); KEEPF(W.y); KEEPF(W.z); KEEPF(W.w); } while (0)

__device__ __forceinline__ float sigm_(float x) {
    return 1.0f / (1.0f + __expf(-x));
}
__device__ __forceinline__ float tanh_(float x) {
    float xc = fminf(fmaxf(x, -15.0f), 15.0f);
    float e = __expf(2.0f * xc);
    return 1.0f - 2.0f / (e + 1.0f);
}

// Exact-tag poll of two value slots (value and epoch share one u64 -> 1 hop).
__device__ __forceinline__ void poll2(const u64* p0, const u64* p1, u32 tag,
                                      float* o0, float* o1, int* alive) {
    u64 v0 = 0, v1 = 0;
    int d0 = 0, d1 = 0, guard = 0;
    while (*alive) {
        if (!d0) { v0 = __hip_atomic_load(p0, __ATOMIC_RELAXED, __HIP_MEMORY_SCOPE_AGENT); d0 = ((u32)(v0 >> 32) == tag); }
        if (!d1) { v1 = __hip_atomic_load(p1, __ATOMIC_RELAXED, __HIP_MEMORY_SCOPE_AGENT); d1 = ((u32)(v1 >> 32) == tag); }
        if (d0 & d1) break;
        __builtin_amdgcn_s_sleep(2);
        if (++guard > (1 << 20)) *alive = 0;   // fail visibly, never hang
    }
    *o0 = __uint_as_float((u32)v0);
    *o1 = __uint_as_float((u32)v1);
}

// Backpressure: wait until both slots carry tag >= want (signed compare so the
// 0xAA poison pattern, if it ever leaked, reads negative and never passes).
__device__ __forceinline__ void poll2_geq(const u64* p0, const u64* p1, int want,
                                          int* alive) {
    int guard = 0;
    while (*alive) {
        u64 v0 = __hip_atomic_load(p0, __ATOMIC_RELAXED, __HIP_MEMORY_SCOPE_AGENT);
        u64 v1 = __hip_atomic_load(p1, __ATOMIC_RELAXED, __HIP_MEMORY_SCOPE_AGENT);
        if ((int)(u32)(v0 >> 32) >= want && (int)(u32)(v1 >> 32) >= want) break;
        __builtin_amdgcn_s_sleep(2);
        if (++guard > (1 << 20)) *alive = 0;
    }
}

__device__ __forceinline__ void publish1(u64* p, float v, u32 tag) {
    u64 pk = ((u64)tag << 32) | (u64)__float_as_uint(v);
    __hip_atomic_store(p, pk, __ATOMIC_RELAXED, __HIP_MEMORY_SCOPE_AGENT);
}

// ---------------------------------------------------------------------------
// Persistent pipeline kernel. 256 blocks x 1024 threads (1 block/CU).
// Blocks 0..127: layer-1, block owns h1 outputs bid*16..+15 (64 gate rows).
// Blocks 128..255: layer-2, same ownership for h2 + both weight matrices.
// Thread (r=tid&63, ch=tid>>6): local gate row r, cols ch*128..+127.
// ---------------------------------------------------------------------------
__global__ void __launch_bounds__(1024, 4)
pipe_kernel(const float* __restrict__ Whh1, const float* __restrict__ wih1,
            const float* __restrict__ bih1, const float* __restrict__ bhh1,
            const float* __restrict__ Wih2, const float* __restrict__ Whh2,
            const float* __restrict__ bih2, const float* __restrict__ bhh2,
            const float* __restrict__ wl, const float* __restrict__ bl,
            const float* __restrict__ xseq,
            u64* __restrict__ h1ex, u64* __restrict__ h2ex,
            float* __restrict__ H2h, float* __restrict__ out)
{
    __shared__ float lds_ha[HD];     // staged h1
    __shared__ float lds_hb[HD];     // staged h2 (L2 GEMV; L1 future out-proj)
    __shared__ float lds_x[TT];
    __shared__ float lds_wl[HD];
    __shared__ float lds_p[16][64];
    __shared__ float lds_g[64];
    __shared__ float lds_red[16];

    const int tid = threadIdx.x;
    const bool isL2 = blockIdx.x >= 128;
    const int bid = blockIdx.x & 127;
    const int r = tid & 63;          // local gate row
    const int ch = tid >> 6;         // column chunk (128 cols)
    const int grow = (r >> 4) * HD + bid * 16 + (r & 15);
    const int e0 = tid * 2, e1 = tid * 2 + 1;
    const int lane = tid & 63, wid = tid >> 6;

    // -------- resident weights (pinned via asm barrier) --------
    float4 wa[32], wb[32];
    if (!isL2) {
        const float* s1 = Whh1 + (size_t)grow * HD + ch * 128;
        #pragma unroll
        for (int i = 0; i < 32; ++i) { wa[i] = LD4(s1 + 4 * i); KEEP4(wa[i]); }
    } else {
        const float* s1 = Wih2 + (size_t)grow * HD + ch * 128;
        const float* s2 = Whh2 + (size_t)grow * HD + ch * 128;
        #pragma unroll
        for (int i = 0; i < 32; ++i) { wa[i] = LD4(s1 + 4 * i); KEEP4(wa[i]); }
        #pragma unroll
        for (int i = 0; i < 32; ++i) { wb[i] = LD4(s2 + 4 * i); KEEP4(wb[i]); }
    }

    float myb = 0.0f, myaiv = 0.0f;
    if (tid < 64) {   // reducer lane: handles local row tid (ch==0 -> grow ok)
        myb = isL2 ? (bih2[grow] + bhh2[grow]) : (bih1[grow] + bhh1[grow]);
        myaiv = isL2 ? 0.0f : wih1[grow];
    }
    lds_x[e0] = xseq[e0];  lds_x[e1] = xseq[e1];
    lds_wl[e0] = wl[e0];   lds_wl[e1] = wl[e1];
    const float blin = bl[0];
    float c = 0.0f;          // cell state: wave0 lanes 0..15
    int alive = 1;
    __syncthreads();

    if (!isL2) {
        // ================= layer 1 =================
        #pragma unroll 1
        for (int t = 0; t < TT + FUT; ++t) {
            float xcur;
            // stage h1(t-1) from ring slot (t-1)%NS, tag t
            if (t == 0) {
                lds_ha[e0] = 0.0f; lds_ha[e1] = 0.0f;
            } else {
                u64* s = h1ex + (size_t)((t - 1) & (NS - 1)) * HD;
                poll2(s + e0, s + e1, (u32)t, &lds_ha[e0], &lds_ha[e1], &alive);
            }
            if (t < TT) {
                // backpressure: before overwriting h1 slot t%NS (holds h1(t-NS)),
                // ensure every L2 block finished step t-NS (tag >= t-NS+1).
                if (t >= NS) {
                    const u64* s2 = h2ex + (size_t)(t & (NS - 1)) * HD;
                    poll2_geq(s2 + e0, s2 + e1, t - NS + 1, &alive);
                }
                __syncthreads();
                xcur = lds_x[t];
            } else {
                // future: x(t) = out(t-1) = wl . h2(t-1) + bl (redundant per block)
                u64* s2 = h2ex + (size_t)((t - 1) & (NS - 1)) * HD;
                poll2(s2 + e0, s2 + e1, (u32)t, &lds_hb[e0], &lds_hb[e1], &alive);
                __syncthreads();
                float sd = fmaf(lds_wl[e0], lds_hb[e0], lds_wl[e1] * lds_hb[e1]);
                #pragma unroll
                for (int off = 32; off > 0; off >>= 1) sd += __shfl_down(sd, off);
                if (lane == 0) lds_red[wid] = sd;
                __syncthreads();
                float ss = 0.0f;
                #pragma unroll
                for (int k2 = 0; k2 < 16; ++k2) ss += lds_red[k2];
                xcur = ss + blin;
                if (t > TT && tid == 0 && blockIdx.x == 0) out[t - 1] = xcur;
            }

            // GEMV: 128 FMAs vs resident Whh1 rows
            const float* hc = lds_ha + ch * 128;
            float a0 = 0, a1 = 0, a2 = 0, a3 = 0;
            #pragma unroll
            for (int i = 0; i < 32; ++i) {
                float4 hv = LD4(hc + 4 * i);
                a0 = fmaf(wa[i].x, hv.x, a0); a1 = fmaf(wa[i].y, hv.y, a1);
                a2 = fmaf(wa[i].z, hv.z, a2); a3 = fmaf(wa[i].w, hv.w, a3);
            }
            lds_p[ch][r] = (a0 + a1) + (a2 + a3);
            __syncthreads();

            if (tid < 64) {   // wave0: reduce 16 chunks, activate, cell, publish
                float s0 = 0, s1 = 0, s2 = 0, s3 = 0;
                #pragma unroll
                for (int cc = 0; cc < 16; cc += 4) {
                    s0 += lds_p[cc + 0][tid]; s1 += lds_p[cc + 1][tid];
                    s2 += lds_p[cc + 2][tid]; s3 += lds_p[cc + 3][tid];
                }
                float gv = (s0 + s1) + (s2 + s3) + myb + myaiv * xcur;
                lds_g[tid] = ((tid >> 4) == 2) ? tanh_(gv) : sigm_(gv);
                if (tid < 16) {   // same-wave ordering: writes above precede reads
                    float gi = lds_g[tid],      gf = lds_g[16 + tid];
                    float gg = lds_g[32 + tid], go = lds_g[48 + tid];
                    c = gf * c + gi * gg;
                    float h = go * tanh_(c);
                    publish1(h1ex + (size_t)(t & (NS - 1)) * HD + bid * 16 + tid,
                             h, (u32)(t + 1));
                }
            }
        }
        // epilogue: out[2175] from h2(2175)
        if (blockIdx.x == 0) {
            u64* s2 = h2ex + (size_t)((TT + FUT - 1) & (NS - 1)) * HD;
            poll2(s2 + e0, s2 + e1, (u32)(TT + FUT), &lds_hb[e0], &lds_hb[e1], &alive);
            __syncthreads();
            float sd = fmaf(lds_wl[e0], lds_hb[e0], lds_wl[e1] * lds_hb[e1]);
            #pragma unroll
            for (int off = 32; off > 0; off >>= 1) sd += __shfl_down(sd, off);
            if (lane == 0) lds_red[wid] = sd;
            __syncthreads();
            if (tid == 0) {
                float ss = 0.0f;
                #pragma unroll
                for (int k2 = 0; k2 < 16; ++k2) ss += lds_red[k2];
                out[TT + FUT - 1] = ss + blin;
            }
        }
    } else {
        // ================= layer 2 (uniform across all 2176 steps) =========
        #pragma unroll 1
        for (int t = 0; t < TT + FUT; ++t) {
            // stage h2(t-1)
            if (t == 0) {
                lds_hb[e0] = 0.0f; lds_hb[e1] = 0.0f;
            } else {
                u64* s = h2ex + (size_t)((t - 1) & (NS - 1)) * HD;
                poll2(s + e0, s + e1, (u32)t, &lds_hb[e0], &lds_hb[e1], &alive);
            }
            // stage h1(t) (tag t+1)
            {
                u64* s = h1ex + (size_t)(t & (NS - 1)) * HD;
                poll2(s + e0, s + e1, (u32)(t + 1), &lds_ha[e0], &lds_ha[e1], &alive);
            }
            __syncthreads();

            // GEMV: 256 FMAs vs resident Wih2 (x=h1(t)) + Whh2 (h2(t-1))
            const float* h1c = lds_ha + ch * 128;
            const float* h2c = lds_hb + ch * 128;
            float a0 = 0, a1 = 0, a2 = 0, a3 = 0;
            #pragma unroll
            for (int i = 0; i < 32; ++i) {
                float4 hv = LD4(h1c + 4 * i);
                a0 = fmaf(wa[i].x, hv.x, a0); a1 = fmaf(wa[i].y, hv.y, a1);
                a2 = fmaf(wa[i].z, hv.z, a2); a3 = fmaf(wa[i].w, hv.w, a3);
            }
            #pragma unroll
            for (int i = 0; i < 32; ++i) {
                float4 hv = LD4(h2c + 4 * i);
                a0 = fmaf(wb[i].x, hv.x, a0); a1 = fmaf(wb[i].y, hv.y, a1);
                a2 = fmaf(wb[i].z, hv.z, a2); a3 = fmaf(wb[i].w, hv.w, a3);
            }
            lds_p[ch][r] = (a0 + a1) + (a2 + a3);
            __syncthreads();

            if (tid < 64) {
                float s0 = 0, s1 = 0, s2 = 0, s3 = 0;
                #pragma unroll
                for (int cc = 0; cc < 16; cc += 4) {
                    s0 += lds_p[cc + 0][tid]; s1 += lds_p[cc + 1][tid];
                    s2 += lds_p[cc + 2][tid]; s3 += lds_p[cc + 3][tid];
                }
                float gv = (s0 + s1) + (s2 + s3) + myb;
                lds_g[tid] = ((tid >> 4) == 2) ? tanh_(gv) : sigm_(gv);
                if (tid < 16) {
                    float gi = lds_g[tid],      gf = lds_g[16 + tid];
                    float gg = lds_g[32 + tid], go = lds_g[48 + tid];
                    c = gf * c + gi * gg;
                    float h = go * tanh_(c);
                    if (t < TT) H2h[(size_t)t * HD + bid * 16 + tid] = h;
                    publish1(h2ex + (size_t)(t & (NS - 1)) * HD + bid * 16 + tid,
                             h, (u32)(t + 1));
                }
            }
        }
    }
}

// ---------------------------------------------------------------------------
// out[t] = b_lin + sum_k H2[t][k]*w_lin[k],  t in [0,2048)
// ---------------------------------------------------------------------------
__global__ void __launch_bounds__(256)
outs_kernel(const float* __restrict__ H2h, const float* __restrict__ wl,
            const float* __restrict__ bl, float* __restrict__ out)
{
    const int t = blockIdx.x;
    const int tid = threadIdx.x;
    const float* h = H2h + (size_t)t * HD + tid * 8;
    const float* wp = wl + tid * 8;
    float4 h0 = LD4(h), h1 = LD4(h + 4);
    float4 w0 = LD4(wp), w1 = LD4(wp + 4);
    float s = h0.x * w0.x;
    s = fmaf(h0.y, w0.y, s); s = fmaf(h0.z, w0.z, s); s = fmaf(h0.w, w0.w, s);
    s = fmaf(h1.x, w1.x, s); s = fmaf(h1.y, w1.y, s);
    s = fmaf(h1.z, w1.z, s); s = fmaf(h1.w, w1.w, s);
    #pragma unroll
    for (int off = 32; off > 0; off >>= 1) s += __shfl_down(s, off, 64);
    __shared__ float red[4];
    if ((tid & 63) == 0) red[tid >> 6] = s;
    __syncthreads();
    if (tid == 0) out[t] = red[0] + red[1] + red[2] + red[3] + bl[0];
}

// ---------------------------------------------------------------------------

extern "C" void kernel_launch(void* const* d_in, const int* in_sizes, int n_in,
                              void* d_out, int out_size, void* d_ws, size_t ws_size,
                              hipStream_t stream) {
    const float* input = (const float*)d_in[0];
    const float* w_ih1 = (const float*)d_in[1];
    const float* w_hh1 = (const float*)d_in[2];
    const float* b_ih1 = (const float*)d_in[3];
    const float* b_hh1 = (const float*)d_in[4];
    const float* w_ih2 = (const float*)d_in[5];
    const float* w_hh2 = (const float*)d_in[6];
    const float* b_ih2 = (const float*)d_in[7];
    const float* b_hh2 = (const float*)d_in[8];
    const float* w_lin = (const float*)d_in[9];
    const float* b_lin = (const float*)d_in[10];
    float* out = (float*)d_out;

    char* ws = (char*)d_ws;
    u64*   h1ex = (u64*)(ws);                       // 16*2048*8 = 256 KB
    u64*   h2ex = (u64*)(ws + 262144);              // 256 KB
    float* H2h  = (float*)(ws + 524288);            // 16 MB

    // zero both exchange rings (ws is re-poisoned to 0xAA before every launch)
    hipMemsetAsync(ws, 0, 524288, stream);

    // ---- persistent pipelined recurrence (all 2176 steps, both layers) ----
    {
        const float* a0 = w_hh1; const float* a1 = w_ih1;
        const float* a2 = b_ih1; const float* a3 = b_hh1;
        const float* a4 = w_ih2; const float* a5 = w_hh2;
        const float* a6 = b_ih2; const float* a7 = b_hh2;
        const float* a8 = w_lin; const float* a9 = b_lin;
        const float* a10 = input;
        u64* a11 = h1ex; u64* a12 = h2ex;
        float* a13 = H2h; float* a14 = out;
        void* args[] = {&a0, &a1, &a2, &a3, &a4, &a5, &a6, &a7, &a8, &a9,
                        &a10, &a11, &a12, &a13, &a14};
        if (hipLaunchCooperativeKernel((const void*)pipe_kernel, dim3(256), dim3(1024),
                                       args, 0, stream) != hipSuccess) {
            (void)hipGetLastError();
            hipLaunchKernelGGL(pipe_kernel, dim3(256), dim3(1024), 0, stream,
                               a0, a1, a2, a3, a4, a5, a6, a7, a8, a9,
                               a10, a11, a12, a13, a14);
        }
    }

    // ---- out[0..2047] from H2 history ----
    hipLaunchKernelGGL(outs_kernel, dim3(TT), dim3(256), 0, stream,
                       H2h, w_lin, b_lin, out);
}